// Round 8
// baseline (326.421 us; speedup 1.0000x reference)
//
#include <hip/hip_runtime.h>
#include <hip/hip_bf16.h>

// ProtoLayer: dists_to_protos[n][p] = |f_n|^2 + |p_p|^2 - 2 f_n.p_p  (N x P)
//             dists_to_latents      = transpose of the above          (P x N)
// N=65536, P=512, D=256, fp32 in/out. Memory-bound (~332 MB traffic, floor ~53us).
// R9: L2 write-combining experiment. dist ~153us vs 53us floor; R3==R6==R8
//     (store run length, barriers, epilogue style ALL irrelevant) + cycle models
//     say compute/L2/issue cost ~15-20% of observed => remaining suspect is
//     DRAM write locality: nontemporal (no-allocate) stores emit isolated
//     128-256B bursts at 2KB/256KB strides -> fresh row activation each, ~25%
//     row utilization ~ 2.2 TB/s effective, matching 153us. Changes vs R8:
//     (a) output stores are PLAIN (L2-allocating) so a block's scattered
//         pieces combine into full dirty lines/rows before eviction; nt kept
//         on feat loads only.
//     (b) m204 bijective XCD-contiguous block swizzle: co-resident blocks on
//         one XCD now cover adjacent n-chunks, so their out1 writes to the
//         same p-row are contiguous in the same XCD L2 -> multi-KB combined
//         evictions. (Round-robin dispatch previously scattered neighbors
//         across non-coherent L2s: combining was impossible.)
//     K-loop (pre-swizzled B fragments, R7's -31us win) and barrier-free
//     epilogue structure unchanged.

#define DD 256
#define PP 512
#define BN 64
#define AP 280   // A slab row stride in bf16 elems (256 + 24 pad)
#define TP 36    // transpose tile n-stride in dwords (32 + 4; *4B = 144, 16B-aligned)

typedef short bf16x8 __attribute__((ext_vector_type(8)));
typedef float f32x16 __attribute__((ext_vector_type(16)));
typedef float f32x4 __attribute__((ext_vector_type(4)));
typedef unsigned short u16x4 __attribute__((ext_vector_type(4)));

__device__ __forceinline__ unsigned short f2bf(float f) {
    unsigned int u = __builtin_bit_cast(unsigned int, f);
    u = (u + 0x7fffu + ((u >> 16) & 1u)) >> 16;   // RNE
    return (unsigned short)u;
}

// --- prep: proto fp32 -> bf16 MFMA-fragment layout + proto_sq fp32 ---
// Fragment word (16B) at ((tile*16 + kk)*64 + fl)*8 holds
//   B[p = tile*32 + (fl&31)][k = kk*16 + (fl>>5)*8 + 0..7]
// i.e. exactly the bf16x8 the 32x32x16 MFMA B-operand wants from lane fl.
__global__ __launch_bounds__(256) void proto_prep(const float* __restrict__ proto,
                                                  unsigned short* __restrict__ bwf,
                                                  float* __restrict__ psq) {
    const int w = threadIdx.x >> 6, lane = threadIdx.x & 63;
    const int l31 = lane & 31, hf = lane >> 5;
    const int row = blockIdx.x * 8 + w * 2 + hf;        // 64 blocks * 8 rows
    const int oct = l31;                                // k-octet 0..31
    const float* src = proto + (size_t)row * DD + oct * 8;
    const f32x4 f0 = *(const f32x4*)(src);
    const f32x4 f1 = *(const f32x4*)(src + 4);
    bf16x8 b;
    b[0] = (short)f2bf(f0.x); b[1] = (short)f2bf(f0.y);
    b[2] = (short)f2bf(f0.z); b[3] = (short)f2bf(f0.w);
    b[4] = (short)f2bf(f1.x); b[5] = (short)f2bf(f1.y);
    b[6] = (short)f2bf(f1.z); b[7] = (short)f2bf(f1.w);
    const int tile = row >> 5;
    const int kk = oct >> 1;
    const int fl = ((oct & 1) << 5) | (row & 31);
    *(bf16x8*)(bwf + ((size_t)(tile * 16 + kk) * 64 + fl) * 8) = b;

    float part = f0.x * f0.x + f0.y * f0.y + f0.z * f0.z + f0.w * f0.w
               + f1.x * f1.x + f1.y * f1.y + f1.z * f1.z + f1.w * f1.w;
    // reduce across the 32-lane half (offsets < 32 stay within the half)
    #pragma unroll
    for (int o = 16; o > 0; o >>= 1) part += __shfl_xor(part, o, 64);
    if (l31 == 0) psq[row] = part;
}

// --- main: block = 8 waves, 64 feature rows x all 512 prototypes ---
__global__ __launch_bounds__(512, 4) void proto_dist(
        const float* __restrict__ feat,
        const unsigned short* __restrict__ bw,
        const float* __restrict__ psq,
        float* __restrict__ out0,   // [N][512]
        float* __restrict__ out1,   // [512][N]
        int N) {
    __shared__ unsigned short A_lds[BN * AP];           // 35840 B
    __shared__ float Strans[8 * 32 * TP];               // 36864 B (per-wave tiles)
    __shared__ float fsq[BN];

    const int tid = threadIdx.x;
    const int w = tid >> 6, lane = tid & 63;

    // m204 bijective XCD-contiguous swizzle: dispatch index -> work id so that
    // each XCD (hw: consecutive dispatch ids round-robin XCDs) processes a
    // CONTIGUOUS band of n-chunks; co-resident blocks then write adjacent
    // out1 columns into the same XCD L2 (write-combining).
    const int nwg = gridDim.x;
    const int q = nwg >> 3, rr8 = nwg & 7;
    const int xcd = blockIdx.x & 7, lot = blockIdx.x >> 3;
    const int wg = (xcd < rr8 ? xcd * (q + 1) : rr8 * (q + 1) + (xcd - rr8) * q) + lot;
    const int n0 = wg * BN;

    // stage A: fp32 global -> bf16 LDS (coalesced; feat read exactly once)
    #pragma unroll
    for (int i = 0; i < 8; ++i) {
        const int row = i * 8 + w;
        const f32x4 f = __builtin_nontemporal_load(
            (const f32x4*)(feat + (size_t)(n0 + row) * DD + lane * 4));
        u16x4 u;
        u.x = f2bf(f.x); u.y = f2bf(f.y); u.z = f2bf(f.z); u.w = f2bf(f.w);
        *(u16x4*)&A_lds[row * AP + lane * 4] = u;
        float part = f.x * f.x + f.y * f.y + f.z * f.z + f.w * f.w;
        for (int o = 32; o > 0; o >>= 1) part += __shfl_xor(part, o, 64);
        if (lane == 0) fsq[row] = part;
    }
    __syncthreads();   // the ONLY barrier in this kernel

    const int r = w & 1;            // n-tile (32 rows)
    const int g = w >> 1;           // p-group (128 cols)
    const int colT = g * 128;
    const int l31 = lane & 31;
    const int hi = lane >> 5;

    // A operand: A[m = lane&31][k = (lane>>5)*8 + j]
    const unsigned short* arow = &A_lds[(32 * r + l31) * AP + hi * 8];
    // B fragments for this wave's 4 tiles: base + (t*16 + kk)*512 + lane*8
    const unsigned short* bwf_w = bw + (size_t)g * 4 * 16 * 512;

    f32x16 acc[4];
    #pragma unroll
    for (int t = 0; t < 4; ++t)
        #pragma unroll
        for (int e = 0; e < 16; ++e) acc[t][e] = 0.0f;

    #pragma unroll 2
    for (int kk = 0; kk < 16; ++kk) {
        const bf16x8 a = *(const bf16x8*)(arow + kk * 16);
        #pragma unroll
        for (int t = 0; t < 4; ++t) {
            const bf16x8 b = *(const bf16x8*)(bwf_w + ((t * 16 + kk) * 64 + lane) * 8);
            acc[t] = __builtin_amdgcn_mfma_f32_32x32x16_bf16(a, b, acc[t], 0, 0, 0);
        }
    }

    // per-lane epilogue constants (fsq written pre-barrier; ordered)
    f32x4 fsq_q[4];
    #pragma unroll
    for (int q2 = 0; q2 < 4; ++q2)
        fsq_q[q2] = *(const f32x4*)&fsq[32 * r + 8 * q2 + 4 * hi];

    float* trans = Strans + w * (32 * TP);   // per-wave private 32x36 fp32
    float* out0_base = out0 + (size_t)(n0 + 32 * r) * PP;

    #pragma unroll
    for (int t = 0; t < 4; ++t) {
        const int p = colT + 32 * t + l31;
        const float psq_v = psq[p];
        // C/D layout (m74/m101): col=lane&31 (p), row=(reg&3)+8*(reg>>2)+4*hi (n)
        #pragma unroll
        for (int q2 = 0; q2 < 4; ++q2) {
            f32x4 d;
            #pragma unroll
            for (int e = 0; e < 4; ++e) {
                const int n_l = e + 8 * q2 + 4 * hi;
                const float dist = fsq_q[q2][e] + psq_v - 2.0f * acc[t][4 * q2 + e];
                d[e] = dist;
                out0_base[(size_t)n_l * PP + p] = dist;   // plain: L2-combining
            }
            // p-major transpose tile: row = p-local (l31), 4 consecutive n
            *(f32x4*)&trans[l31 * TP + 8 * q2 + 4 * hi] = d;
        }
        // same-wave LDS exchange (in-order DS per wave; lgkmcnt auto-inserted)
        #pragma unroll
        for (int j = 0; j < 4; ++j) {
            const int p_row = j * 8 + (lane >> 3);       // 8 p-rows per instr
            const int n_off = (lane & 7) * 4;            // 8 lanes * 4 n = 32 n
            const f32x4 v = *(const f32x4*)&trans[p_row * TP + n_off];
            *(f32x4*)(out1 + (size_t)(colT + 32 * t + p_row) * N
                            + (n0 + 32 * r + n_off)) = v;  // plain: L2-combining
        }
    }
}

extern "C" void kernel_launch(void* const* d_in, const int* in_sizes, int n_in,
                              void* d_out, int out_size, void* d_ws, size_t ws_size,
                              hipStream_t stream) {
    const float* feat = (const float*)d_in[0];
    const float* proto = (const float*)d_in[1];
    const int N = in_sizes[0] / DD;          // 65536

    unsigned short* bw = (unsigned short*)d_ws;                // 512*256*2 = 256 KB
    float* psq = (float*)((char*)d_ws + (size_t)PP * DD * 2);  // +2 KB

    float* out0 = (float*)d_out;
    float* out1 = out0 + (size_t)N * PP;

    proto_prep<<<PP / 8, 256, 0, stream>>>(proto, bw, psq);
    proto_dist<<<N / BN, 512, 0, stream>>>(feat, bw, psq, out0, out1, N);
}